// Round 2
// baseline (105.712 us; speedup 1.0000x reference)
//
#include <hip/hip_runtime.h>
#include <hip/hip_bf16.h>
#include <stdint.h>

#define M_DIM 32
#define K_DIM 8192
#define N_DIM 8192
#define NGROUPS 64
#define GSZ 128
#define KSPLIT 2
#define KHALF (K_DIM / KSPLIT)     // 4096
#define GHALF (NGROUPS / KSPLIT)   // 32
#define BN 64

typedef __attribute__((ext_vector_type(8))) short short8;   // 8 bf16 (4 VGPRs)
typedef __attribute__((ext_vector_type(4))) float floatx4;  // MFMA acc

// ---------------------------------------------------------------------------
// Pre-kernel: A (fp32, 32x8192) -> Abf (bf16, octet-permuted [0,4,1,5,2,6,3,7])
// and R[m][g] = sum over group g of bf16-rounded A (so the 128-term of the
// fused dequant cancels EXACTLY against 136*R).
// grid (32, 4) x 256 threads; each thread handles one octet of 8 k-values.
// ---------------------------------------------------------------------------
__global__ void marlin_prep_kernel(const float* __restrict__ A,
                                   uint16_t* __restrict__ Abf,
                                   float* __restrict__ R) {
    const int m = blockIdx.x;
    const int qtr = blockIdx.y;
    const int t = threadIdx.x;
    const int octet = qtr * 256 + t;     // 0..1023
    const int k0 = octet * 8;

    const float* a = A + m * K_DIM + k0;
    uint16_t b[8];
    float sum = 0.f;
#pragma unroll
    for (int j = 0; j < 8; j++) {
        union { __hip_bfloat16 h; uint16_t u; } cv;
        cv.h = __float2bfloat16(a[j]);   // round-to-nearest bf16
        b[j] = cv.u;
        sum += __bfloat162float(cv.h);   // sum of the ROUNDED values
    }
    // pack in permuted k-order [0,4,1,5,2,6,3,7] to match nibble-pair extract
    uint32_t w0 = (uint32_t)b[0] | ((uint32_t)b[4] << 16);
    uint32_t w1 = (uint32_t)b[1] | ((uint32_t)b[5] << 16);
    uint32_t w2 = (uint32_t)b[2] | ((uint32_t)b[6] << 16);
    uint32_t w3 = (uint32_t)b[3] | ((uint32_t)b[7] << 16);
    uint4 packed = make_uint4(w0, w1, w2, w3);
    *(uint4*)(Abf + (size_t)m * K_DIM + k0) = packed;

    // group = octet/16; threads t..t+15 share a group -> shfl reduce width 16
#pragma unroll
    for (int off = 1; off < 16; off <<= 1) sum += __shfl_xor(sum, off, 16);
    if ((t & 15) == 0) R[m * NGROUPS + qtr * 16 + (t >> 4)] = sum;
}

// ---------------------------------------------------------------------------
// Main kernel: grid (N/64, KSPLIT) x 512 threads (8 waves).
// Wave w: mtile = w&1 (rows 16*mtile..+15), ntile = w>>1 (cols 16*ntile..+15).
// Per group (K=128 = 4 MFMA k-tiles): acc = sum A*(128+q) via MFMA, then
// C += s * (acc - 136*R).  Epilogue: fp32 atomicAdd into zeroed d_out.
// ---------------------------------------------------------------------------
__global__ __launch_bounds__(512) void
MarlinQuantLinear_68556267979256_kernel(const int* __restrict__ qw,
                                        const float* __restrict__ scales,
                                        const float* __restrict__ bias,
                                        const uint16_t* __restrict__ Abf,
                                        const float* __restrict__ R,
                                        float* __restrict__ out) {
    // A chunk for one group: 32 rows x 128 k, row stride 136 (+8 pad:
    // 272B rows -> bank = 4*row mod 32 -> 2-way aliasing = free)
    __shared__ __align__(16) uint16_t a_lds[32 * 136];
    __shared__ float r_lds[32 * 33];   // this half's rowsums, padded stride 33

    const int bx = blockIdx.x;           // n-tile block
    const int bz = blockIdx.y;           // k-split half
    const int nbase = bx * BN;
    const int kbase = bz * KHALF;
    const int gbase = bz * GHALF;

    const int tid = threadIdx.x;
    const int w = tid >> 6;
    const int lane = tid & 63;
    const int quad = lane >> 4;
    const int l16 = lane & 15;
    const int mtile = w & 1;
    const int ntile = w >> 1;
    const int ncol = nbase + ntile * 16 + l16;

    // stage this half's R into LDS (32m x 32g)
    {
        int i = tid;
#pragma unroll
        for (int rep = 0; rep < 2; rep++, i += 512) {
            int mm = i >> 5, gg = i & 31;
            r_lds[mm * 33 + gg] = R[mm * NGROUPS + gbase + gg];
        }
    }

    // cooperative A-chunk load mapping: thread -> (row lm, 8-elem segment lseg)
    const int lm = tid >> 4;     // 0..31
    const int lseg = tid & 15;   // 0..15
    const uint4* Asrc = (const uint4*)Abf;                 // 8 bf16 per uint4
    const int abase = lm * (K_DIM / 8) + (kbase >> 3) + lseg;

    const int kp_base = kbase >> 3;      // qweight packed-row base
    floatx4 C = {0.f, 0.f, 0.f, 0.f};

    for (int g = 0; g < GHALF; g++) {
        __syncthreads();   // protect a_lds from previous iteration's readers
        {
            uint4 av = Asrc[abase + g * 16];
            *(uint4*)&a_lds[lm * 136 + lseg * 8] = av;
        }
        __syncthreads();

        const float s = scales[(gbase + g) * N_DIM + ncol];
        floatx4 accg = {0.f, 0.f, 0.f, 0.f};
#pragma unroll
        for (int t = 0; t < 4; t++) {
            // one int32 = exactly this lane's 8-nibble B fragment
            const uint32_t q =
                (uint32_t)qw[(kp_base + g * 16 + t * 4 + quad) * N_DIM + ncol];
            union { uint32_t u[4]; short8 v; } fb;
            fb.u[0] = ( q        & 0x000F000Fu) | 0x43004300u;  // k0,k4
            fb.u[1] = ((q >> 4)  & 0x000F000Fu) | 0x43004300u;  // k1,k5
            fb.u[2] = ((q >> 8)  & 0x000F000Fu) | 0x43004300u;  // k2,k6
            fb.u[3] = ((q >> 12) & 0x000F000Fu) | 0x43004300u;  // k3,k7
            const short8 fa =
                *(const short8*)&a_lds[(mtile * 16 + l16) * 136 + t * 32 + quad * 8];
            accg = __builtin_amdgcn_mfma_f32_16x16x32_bf16(fa, fb.v, accg, 0, 0, 0);
        }
#pragma unroll
        for (int r = 0; r < 4; r++) {
            // FIX(R1): R row must include the wave's mtile offset — the acc
            // row is global m = mtile*16 + quad*4 + r, and R is per-row.
            const float Rv = r_lds[(mtile * 16 + quad * 4 + r) * 33 + g];
            const float tval = fmaf(-136.0f, Rv, accg[r]);  // acc - 136*R
            C[r] = fmaf(s, tval, C[r]);
        }
    }

    const float bv = (bz == 0) ? bias[ncol] : 0.0f;
#pragma unroll
    for (int r = 0; r < 4; r++) {
        const int m = mtile * 16 + quad * 4 + r;   // C/D row = quad*4 + reg
        atomicAdd(&out[(size_t)m * N_DIM + ncol], C[r] + bv);
    }
}

extern "C" void kernel_launch(void* const* d_in, const int* in_sizes, int n_in,
                              void* d_out, int out_size, void* d_ws, size_t ws_size,
                              hipStream_t stream) {
    const float* A      = (const float*)d_in[0];
    const int*   qw     = (const int*)d_in[1];
    const float* scales = (const float*)d_in[2];
    const float* bias   = (const float*)d_in[3];
    float* out = (float*)d_out;

    uint16_t* Abf = (uint16_t*)d_ws;                                   // 512 KB
    float*    R   = (float*)((char*)d_ws + (size_t)M_DIM * K_DIM * 2); //   8 KB

    hipMemsetAsync(d_out, 0, (size_t)M_DIM * N_DIM * sizeof(float), stream);
    marlin_prep_kernel<<<dim3(M_DIM, 4), 256, 0, stream>>>(A, Abf, R);
    MarlinQuantLinear_68556267979256_kernel<<<dim3(N_DIM / BN, KSPLIT), 512, 0, stream>>>(
        qw, scales, bias, Abf, R, out);
}